// Round 4
// baseline (180.658 us; speedup 1.0000x reference)
//
#include <hip/hip_runtime.h>
#include <stdint.h>

#define Bb 8
#define Ss 2048
#define Dd 4096
#define Ee 64
#define CAP 40
#define M_TOK (Bb*Ss)                   // 16384 tokens
#define TPB 16                          // tokens per k1 block
#define NB1 (M_TOK/TPB)                 // 1024 k1 blocks -> 4/CU
#define NCH (Dd/64)                     // 64 K-chunks of 64
#define NCHK (M_TOK/64)                 // 256 chunks for k3
#define TOP1_OFF  (M_TOK*Ee)            // 1048576
#define PROBS_OFF (TOP1_OFF + M_TOK)    // 1064960
#define AUX_OFF   (PROBS_OFF + M_TOK*Ee)// 2113536
#define ND_OFF    (AUX_OFF + 1)         // 2113537
#define ROWB 272                        // LDS bytes/token row: [hi 128][lo 128][pad 16]
#define BUFB (TPB*ROWB)                 // 4352

typedef __attribute__((ext_vector_type(8))) short short8;
typedef __attribute__((ext_vector_type(4))) float f32x4;

__device__ __forceinline__ ushort f2bf(float x) {   // fp32 -> bf16 bits, RNE
  union { float f; unsigned u; } v; v.f = x;
  return (ushort)((v.u + 0x7fffu + ((v.u >> 16) & 1u)) >> 16);
}
__device__ __forceinline__ float bf2f(ushort b) {
  union { float f; unsigned u; } v; v.u = ((unsigned)b) << 16; return v.f;
}

// ---------------- k0: W [k][e] fp32 -> ws hi/lo bf16 transposed [e][k] ------
__global__ __launch_bounds__(256) void k0_wsplit(const float* __restrict__ W,
                                                 ushort* __restrict__ wh) {
  ushort* wl = wh + (size_t)Dd * Ee;
  const int l  = threadIdx.x & 63;            // lane = expert
  const int wv = threadIdx.x >> 6;
  const int kb = blockIdx.x * 64 + wv * 16;   // 16 k-rows per wave
  ushort hi[16], lo[16];
#pragma unroll
  for (int j = 0; j < 16; ++j) {              // coalesced: 64 lanes read row k
    const float x = W[(size_t)(kb + j) * Ee + l];
    const ushort h = f2bf(x);
    hi[j] = h;
    lo[j] = f2bf(x - bf2f(h));
  }
  const size_t o = (size_t)l * Dd + kb;
  short8 h0, h1, l0, l1;
#pragma unroll
  for (int j = 0; j < 8; ++j) {
    h0[j] = (short)hi[j]; h1[j] = (short)hi[8 + j];
    l0[j] = (short)lo[j]; l1[j] = (short)lo[8 + j];
  }
  *(short8*)(wh + o) = h0; *(short8*)(wh + o + 8) = h1;
  *(short8*)(wl + o) = l0; *(short8*)(wl + o + 8) = l1;
}

// ---------------- k1: MFMA logits + softmax + argmax + chunk stats ----------
__global__ __launch_bounds__(256, 4) void k1_router(
    const float* __restrict__ H, const ushort* __restrict__ wh,
    const float* __restrict__ bias, float* __restrict__ out,
    int* __restrict__ cnt_ws, float* __restrict__ pi_ws,
    int* __restrict__ eid_ws) {
  __shared__ char lds[2 * BUFB];               // 8704 B
  const int tid = threadIdx.x;
  const int wv  = tid >> 6, l = tid & 63;
  const int tb  = blockIdx.x * TPB;
  const ushort* wlp = wh + (size_t)Dd * Ee;

  f32x4 acc = {0.f, 0.f, 0.f, 0.f};

  float4 stA, stB;                             // depth-2 H stage regs
#define PREF(dst, c) {                                                        \
    dst = *(const float4*)(H + (size_t)(tb + (tid >> 4)) * Dd + (c) * 64 +    \
                           (tid & 15) * 4); }

#define WRT(stv, bufp) {                                                      \
    const ushort hx = f2bf(stv.x), hy = f2bf(stv.y),                          \
                 hz = f2bf(stv.z), hw = f2bf(stv.w);                          \
    uint2 hp, lp;                                                             \
    hp.x = (unsigned)hx | ((unsigned)hy << 16);                               \
    hp.y = (unsigned)hz | ((unsigned)hw << 16);                               \
    lp.x = (unsigned)f2bf(stv.x - bf2f(hx)) |                                 \
           ((unsigned)f2bf(stv.y - bf2f(hy)) << 16);                          \
    lp.y = (unsigned)f2bf(stv.z - bf2f(hz)) |                                 \
           ((unsigned)f2bf(stv.w - bf2f(hw)) << 16);                          \
    *(uint2*)((bufp) + (tid >> 4) * ROWB + (tid & 15) * 8) = hp;              \
    *(uint2*)((bufp) + (tid >> 4) * ROWB + 128 + (tid & 15) * 8) = lp; }

  const size_t boff = (size_t)(wv * 16 + (l & 15)) * Dd + (l >> 4) * 8;
  const ushort* bh_p = wh  + boff;
  const ushort* bl_p = wlp + boff;
  const int aoff = (l & 15) * ROWB + (l >> 4) * 16;

#define BLOAD(d0, d1, d2, d3, c) {                                            \
    d0 = *(const short8*)(bh_p + (c) * 64);                                   \
    d1 = *(const short8*)(bh_p + (c) * 64 + 32);                              \
    d2 = *(const short8*)(bl_p + (c) * 64);                                   \
    d3 = *(const short8*)(bl_p + (c) * 64 + 32); }

#define COMPUTE(bufp, b0, b1, b2, b3) {                                       \
    const char* ab = (bufp) + aoff;                                           \
    short8 ah = *(const short8*)(ab);                                         \
    short8 al = *(const short8*)(ab + 128);                                   \
    acc = __builtin_amdgcn_mfma_f32_16x16x32_bf16(ah, b0, acc, 0, 0, 0);      \
    acc = __builtin_amdgcn_mfma_f32_16x16x32_bf16(ah, b2, acc, 0, 0, 0);      \
    acc = __builtin_amdgcn_mfma_f32_16x16x32_bf16(al, b0, acc, 0, 0, 0);      \
    acc = __builtin_amdgcn_mfma_f32_16x16x32_bf16(al, b2, acc, 0, 0, 0);      \
    ah = *(const short8*)(ab + 64);                                           \
    al = *(const short8*)(ab + 192);                                          \
    acc = __builtin_amdgcn_mfma_f32_16x16x32_bf16(ah, b1, acc, 0, 0, 0);      \
    acc = __builtin_amdgcn_mfma_f32_16x16x32_bf16(ah, b3, acc, 0, 0, 0);      \
    acc = __builtin_amdgcn_mfma_f32_16x16x32_bf16(al, b1, acc, 0, 0, 0);      \
    acc = __builtin_amdgcn_mfma_f32_16x16x32_bf16(al, b3, acc, 0, 0, 0); }

  char* buf0 = lds;
  char* buf1 = lds + BUFB;
  short8 bA0, bA1, bA2, bA3, bB0, bB1, bB2, bB3;

  PREF(stA, 0); PREF(stB, 1);
  BLOAD(bA0, bA1, bA2, bA3, 0);

  for (int cc = 0; cc < 32; ++cc) {
    const int c0 = 2 * cc;
    WRT(stA, buf0);                            // waits vmcnt(stA) only
    if (cc < 31) PREF(stA, c0 + 2);            // 1.5-chunk window
    __syncthreads();
    BLOAD(bB0, bB1, bB2, bB3, c0 + 1);         // L2 prefetch, used next chunk
    COMPUTE(buf0, bA0, bA1, bA2, bA3);
    WRT(stB, buf1);
    if (cc < 31) PREF(stB, c0 + 3);
    __syncthreads();
    if (cc < 31) BLOAD(bA0, bA1, bA2, bA3, c0 + 2);
    COMPUTE(buf1, bB0, bB1, bB2, bB3);
  }

  // ------- epilogue: C-frag -> LDS [16][65] fp32 -> shuffle softmax --------
  __syncthreads();                             // all waves done with tiles
  float* lg = (float*)lds;
  const int col = wv * 16 + (l & 15);
  const int r0  = (l >> 4) * 4;
#pragma unroll
  for (int r = 0; r < 4; ++r) lg[(r0 + r) * 65 + col] = acc[r];
  int*   csh = (int*)(lds + 4608);
  float* psh = (float*)(lds + 4608 + 1024);
  __syncthreads();

  int cnt = 0; float pis = 0.f;
  const float bl_ = bias[l];
#pragma unroll
  for (int i = 0; i < 4; ++i) {                // wave owns 4 rows, lane=expert
    const int t = wv * 4 + i, tok = tb + t;
    const float v = lg[t * 65 + l] + bl_;
    float m = v; int mi = l;
#pragma unroll
    for (int off = 32; off >= 1; off >>= 1) {  // max + first-index argmax
      const float ov = __shfl_xor(m, off);
      const int   oi = __shfl_xor(mi, off);
      if (ov > m || (ov == m && oi < mi)) { m = ov; mi = oi; }
    }
    const float ex = __expf(v - m);
    float ssum = ex;
#pragma unroll
    for (int off = 32; off >= 1; off >>= 1) ssum += __shfl_xor(ssum, off);
    const float inv = 1.0f / ssum;
    const float p = ex * inv;
    out[(size_t)PROBS_OFF + (size_t)tok * Ee + l] = p;
    if (l == 0) {
      out[TOP1_OFF + tok] = inv;               // max prob = 1/sum
      eid_ws[tok] = mi;
    }
    cnt += (mi == l) ? 1 : 0;
    pis += p;
  }
  csh[wv * 64 + l] = cnt;
  psh[wv * 64 + l] = pis;
  __syncthreads();
  if (tid < 64) {
    const int   ct = csh[tid] + csh[64 + tid] + csh[128 + tid] + csh[192 + tid];
    const float pp = psh[tid] + psh[64 + tid] + psh[128 + tid] + psh[192 + tid];
    cnt_ws[blockIdx.x * 64 + tid] = ct;
    pi_ws [blockIdx.x * 64 + tid] = pp;
  }
}

// ---------------- k3: capacity mask + one-hot write + aux/dropped -----------
__global__ __launch_bounds__(64) void k3_indices(
    const int* __restrict__ cnt_ws, const float* __restrict__ pi_ws,
    const int* __restrict__ eid_ws, float* __restrict__ out) {
  __shared__ float tile[64][64];
  const int g    = blockIdx.x;                 // 64-token chunk
  const int lane = threadIdx.x;
  const int b    = g >> 5;                     // 32 chunks per batch row
  const int c    = g & 31;
  const int tok  = g * 64 + lane;
  const int e    = eid_ws[tok];

  unsigned long long mymask = 0ull;            // rank within chunk
  for (int j = 0; j < 64; ++j) {
    const int ej = __shfl(e, j);
    const unsigned long long bal = __ballot(ej == e);
    if (j == lane) mymask = bal;
  }
  const int lrank = __popcll(mymask & ((1ull << lane) - 1ull));

  int prefix = 0;                              // 4 k1-blocks (16 tok) per chunk
  for (int cc = 0; cc < 4 * c; ++cc) prefix += cnt_ws[(b * 128 + cc) * 64 + e];

  const float keep = (prefix + lrank < CAP) ? 1.0f : 0.0f;

#pragma unroll
  for (int j = 0; j < 64; ++j) tile[j][lane] = 0.f;
  __syncthreads();
  tile[lane][e] = keep;
  __syncthreads();

  float4*       og = (float4*)(out + (size_t)g * 64 * 64);
  const float4* ts = (const float4*)&tile[0][0];
#pragma unroll
  for (int i = 0; i < 16; ++i) og[i * 64 + lane] = ts[i * 64 + lane];

  if (g == 0) {                                // aux loss + num_dropped
    float auxsum = 0.f; int dropped = 0;
    for (int bb = 0; bb < 8; ++bb) {
      int tot = 0; float psum = 0.f;
      for (int cc = 0; cc < 128; ++cc) {
        tot  += cnt_ws[(bb * 128 + cc) * 64 + lane];
        psum += pi_ws [(bb * 128 + cc) * 64 + lane];
      }
      dropped += (tot > CAP) ? (tot - CAP) : 0;
      const float fi = (float)((tot < CAP) ? tot : CAP) * (1.0f / (float)Ss);
      const float pi = psum * (1.0f / (float)Ss);
      float fp = fi * pi;
#pragma unroll
      for (int off = 32; off >= 1; off >>= 1) fp += __shfl_xor(fp, off);
      auxsum += fp;
    }
#pragma unroll
    for (int off = 32; off >= 1; off >>= 1) dropped += __shfl_xor(dropped, off);
    if (lane == 0) {
      out[AUX_OFF] = (float)Ee * auxsum / (float)Bb;
      out[ND_OFF]  = (float)dropped;
    }
  }
}

extern "C" void kernel_launch(void* const* d_in, const int* in_sizes, int n_in,
                              void* d_out, int out_size, void* d_ws, size_t ws_size,
                              hipStream_t stream) {
  const float* H    = (const float*)d_in[0];
  const float* Wm   = (const float*)d_in[1];
  const float* bias = (const float*)d_in[2];
  float* out = (float*)d_out;
  ushort* wsp    = (ushort*)d_ws;                              // 1 MB hi+lo bf16
  int*    cnt_ws = (int*)  ((char*)d_ws + (1u << 20));         // 1024*64*4 = 256 KB
  float*  pi_ws  = (float*)((char*)d_ws + (1u << 20) + (256u << 10));
  int*    eid_ws = (int*)  ((char*)d_ws + (1u << 20) + (512u << 10));

  hipLaunchKernelGGL(k0_wsplit, dim3(Dd / 64), dim3(256), 0, stream, Wm, wsp);
  hipLaunchKernelGGL(k1_router, dim3(NB1), dim3(256), 0, stream,
                     H, wsp, bias, out, cnt_ws, pi_ws, eid_ws);
  hipLaunchKernelGGL(k3_indices, dim3(NCHK), dim3(64), 0, stream,
                     cnt_ws, pi_ws, eid_ws, out);
}

// Round 5
// 173.981 us; speedup vs baseline: 1.0384x; 1.0384x over previous
//
#include <hip/hip_runtime.h>
#include <hip/hip_bf16.h>
#include <stdint.h>

#define Bb 8
#define Ss 2048
#define Dd 4096
#define Ee 64
#define CAP 40
#define M_TOK (Bb*Ss)                   // 16384 tokens
#define TPB 16                          // tokens per k1 block (one 16-tok chunk)
#define NB1 (M_TOK/TPB)                 // 1024 k1 blocks
#define NCHK (M_TOK/64)                 // 256 k3 blocks
#define TOP1_OFF  (M_TOK*Ee)            // 1048576
#define PROBS_OFF (TOP1_OFF + M_TOK)    // 1064960
#define AUX_OFF   (PROBS_OFF + M_TOK*Ee)// 2113536
#define ND_OFF    (AUX_OFF + 1)

// ws byte offsets
#define WSF_OFF  0u                          // 1 MB fragment-major W hi/lo
#define CNTT_OFF (1u<<20)                    // 256 KB int   cntT[b][e][cc]
#define PIT_OFF  (CNTT_OFF + (256u<<10))     // 256 KB float piT [b][e][cc]
#define PREF_OFF (PIT_OFF  + (256u<<10))     // 256 KB int   prefT[b][e][cc]
#define EID_OFF  (PREF_OFF + (256u<<10))     // 64 KB int    eid[tok]
#define BST_OFF  (EID_OFF  + (64u<<10))      // 16 floats

typedef __attribute__((ext_vector_type(8))) short short8;
typedef __attribute__((ext_vector_type(4))) float f32x4;

// 8 fp32 -> bf16 hi (RNE) + bf16 lo (residual, RNE), packed as short8
__device__ __forceinline__ void cvt8hl(const float4 a, const float4 b,
                                       short8& hi, short8& lo) {
  __hip_bfloat162 h0 = __float22bfloat162_rn(make_float2(a.x, a.y));
  __hip_bfloat162 h1 = __float22bfloat162_rn(make_float2(a.z, a.w));
  __hip_bfloat162 h2 = __float22bfloat162_rn(make_float2(b.x, b.y));
  __hip_bfloat162 h3 = __float22bfloat162_rn(make_float2(b.z, b.w));
  float2 f0 = __bfloat1622float2(h0), f1 = __bfloat1622float2(h1);
  float2 f2 = __bfloat1622float2(h2), f3 = __bfloat1622float2(h3);
  __hip_bfloat162 l0 = __float22bfloat162_rn(make_float2(a.x - f0.x, a.y - f0.y));
  __hip_bfloat162 l1 = __float22bfloat162_rn(make_float2(a.z - f1.x, a.w - f1.y));
  __hip_bfloat162 l2 = __float22bfloat162_rn(make_float2(b.x - f2.x, b.y - f2.y));
  __hip_bfloat162 l3 = __float22bfloat162_rn(make_float2(b.z - f3.x, b.w - f3.y));
  union U { __hip_bfloat162 h[4]; short8 s; };
  U uh; uh.h[0] = h0; uh.h[1] = h1; uh.h[2] = h2; uh.h[3] = h3; hi = uh.s;
  U ul; ul.h[0] = l0; ul.h[1] = l1; ul.h[2] = l2; ul.h[3] = l3; lo = ul.s;
}

// ---- k0: W [k][e] fp32 -> fragment-major hi/lo bf16 ------------------------
// item (wv,c,l): lane l of expert-group wv, k32-block c. 16B hi @ base, lo @ +1024.
__global__ __launch_bounds__(256) void k0_wsplit(const float* __restrict__ W,
                                                 char* __restrict__ wsf) {
  const int id = blockIdx.x * 256 + threadIdx.x;     // 32768 items
  const int wv = id >> 13;
  const int c  = (id >> 6) & 127;
  const int l  = id & 63;
  const int e  = wv * 16 + (l & 15);
  const int kb = c * 32 + (l >> 4) * 8;
  float xs[8];
#pragma unroll
  for (int j = 0; j < 8; ++j) xs[j] = W[(size_t)(kb + j) * Ee + e];
  short8 hi, lo;
  cvt8hl(make_float4(xs[0], xs[1], xs[2], xs[3]),
         make_float4(xs[4], xs[5], xs[6], xs[7]), hi, lo);
  char* base = wsf + (size_t)(wv * 128 + c) * 2048 + l * 16;
  *(short8*)base = hi;
  *(short8*)(base + 1024) = lo;
}

// ---- k1: register-direct MFMA logits + softmax + argmax + chunk stats ------
__global__ __launch_bounds__(256, 4) void k1_router(
    const float* __restrict__ H, const char* __restrict__ wsf,
    const float* __restrict__ bias, float* __restrict__ out,
    int* __restrict__ cntT, float* __restrict__ piT,
    int* __restrict__ eid_ws) {
  __shared__ float lgs[16 * 65];
  __shared__ int   csh[256];
  __shared__ float psh[256];
  const int tid = threadIdx.x;
  const int wv = tid >> 6, l = tid & 63;
  const int tb = blockIdx.x * TPB;
  const float* hA = H + (size_t)(tb + (l & 15)) * Dd + (l >> 4) * 8;
  const char*  bF = wsf + (size_t)wv * 262144 + l * 16;

  f32x4 acc = {0.f, 0.f, 0.f, 0.f};
  float4 a00, a01, a02, a03, a10, a11, a12, a13;
  short8 b00, b01, b02, b03, b10, b11, b12, b13;

#define LDA(s0, s1, s2, s3, t) { const float* p = hA + (t) * 64;              \
    s0 = *(const float4*)(p);      s1 = *(const float4*)(p + 4);              \
    s2 = *(const float4*)(p + 32); s3 = *(const float4*)(p + 36); }
#define LDB(s0, s1, s2, s3, t) { const char* p = bF + (size_t)(t) * 4096;     \
    s0 = *(const short8*)(p);        s1 = *(const short8*)(p + 1024);         \
    s2 = *(const short8*)(p + 2048); s3 = *(const short8*)(p + 3072); }
#define CMP(x0, x1, x2, x3, c0, c1, c2, c3) {                                 \
    short8 ah, al;                                                            \
    cvt8hl(x0, x1, ah, al);                                                   \
    acc = __builtin_amdgcn_mfma_f32_16x16x32_bf16(ah, c0, acc, 0, 0, 0);      \
    acc = __builtin_amdgcn_mfma_f32_16x16x32_bf16(ah, c1, acc, 0, 0, 0);      \
    acc = __builtin_amdgcn_mfma_f32_16x16x32_bf16(al, c0, acc, 0, 0, 0);      \
    acc = __builtin_amdgcn_mfma_f32_16x16x32_bf16(al, c1, acc, 0, 0, 0);      \
    cvt8hl(x2, x3, ah, al);                                                   \
    acc = __builtin_amdgcn_mfma_f32_16x16x32_bf16(ah, c2, acc, 0, 0, 0);      \
    acc = __builtin_amdgcn_mfma_f32_16x16x32_bf16(ah, c3, acc, 0, 0, 0);      \
    acc = __builtin_amdgcn_mfma_f32_16x16x32_bf16(al, c2, acc, 0, 0, 0);      \
    acc = __builtin_amdgcn_mfma_f32_16x16x32_bf16(al, c3, acc, 0, 0, 0); }

  LDA(a00, a01, a02, a03, 0); LDB(b00, b01, b02, b03, 0);
  for (int t = 0; t < 64; t += 2) {
    LDA(a10, a11, a12, a13, t + 1); LDB(b10, b11, b12, b13, t + 1);
    CMP(a00, a01, a02, a03, b00, b01, b02, b03);
    if (t < 62) { LDA(a00, a01, a02, a03, t + 2); LDB(b00, b01, b02, b03, t + 2); }
    CMP(a10, a11, a12, a13, b10, b11, b12, b13);
  }

  // epilogue: C-frag -> LDS [16][65] -> shuffle softmax/argmax
  const int col = wv * 16 + (l & 15);
  const int r0  = (l >> 4) * 4;
#pragma unroll
  for (int r = 0; r < 4; ++r) lgs[(r0 + r) * 65 + col] = acc[r];
  __syncthreads();

  int cnt = 0; float pis = 0.f;
  const float bl_ = bias[l];
#pragma unroll
  for (int i = 0; i < 4; ++i) {               // wave owns 4 rows, lane=expert
    const int t = wv * 4 + i, tok = tb + t;
    const float v = lgs[t * 65 + l] + bl_;
    float m = v; int mi = l;
#pragma unroll
    for (int off = 32; off >= 1; off >>= 1) { // max + first-index argmax
      const float ov = __shfl_xor(m, off);
      const int   oi = __shfl_xor(mi, off);
      if (ov > m || (ov == m && oi < mi)) { m = ov; mi = oi; }
    }
    const float ex = __expf(v - m);
    float ssum = ex;
#pragma unroll
    for (int off = 32; off >= 1; off >>= 1) ssum += __shfl_xor(ssum, off);
    const float inv = 1.0f / ssum;
    const float p = ex * inv;
    out[(size_t)PROBS_OFF + (size_t)tok * Ee + l] = p;
    if (l == 0) {
      out[TOP1_OFF + tok] = inv;              // max prob = 1/sum
      eid_ws[tok] = mi;
    }
    cnt += (mi == l) ? 1 : 0;
    pis += p;
  }
  csh[wv * 64 + l] = cnt;
  psh[wv * 64 + l] = pis;
  __syncthreads();
  if (tid < 64) {
    const int   ct = csh[tid] + csh[64 + tid] + csh[128 + tid] + csh[192 + tid];
    const float pp = psh[tid] + psh[64 + tid] + psh[128 + tid] + psh[192 + tid];
    const int b = blockIdx.x >> 7, cc = blockIdx.x & 127;
    cntT[((size_t)b * 64 + tid) * 128 + cc] = ct;
    piT [((size_t)b * 64 + tid) * 128 + cc] = pp;
  }
}

// ---- k2: per-(b,e) exclusive prefix over 128 chunks + per-b aux stats ------
__global__ __launch_bounds__(64) void k2_scan(const int* __restrict__ cntT,
                                              const float* __restrict__ piT,
                                              int* __restrict__ prefT,
                                              float* __restrict__ bstat) {
  const int b = blockIdx.x, e = threadIdx.x;   // 8 blocks x 64 lanes
  const int4* src = (const int4*)(cntT + ((size_t)b * 64 + e) * 128);
  int4*       dst = (int4*)(prefT + ((size_t)b * 64 + e) * 128);
  int run = 0;
#pragma unroll 8
  for (int t = 0; t < 32; ++t) {
    const int4 v = src[t];
    int4 o;
    o.x = run; o.y = o.x + v.x; o.z = o.y + v.y; o.w = o.z + v.z;
    run = o.w + v.w;
    dst[t] = o;
  }
  const int tot = run;
  float ps = 0.f;
  const float4* pp = (const float4*)(piT + ((size_t)b * 64 + e) * 128);
#pragma unroll 8
  for (int t = 0; t < 32; ++t) { const float4 v = pp[t]; ps += v.x + v.y + v.z + v.w; }
  const float fi = (float)((tot < CAP) ? tot : CAP) * (1.0f / (float)Ss);
  const float pi = ps * (1.0f / (float)Ss);
  float fp = fi * pi;
  int   dr = (tot > CAP) ? (tot - CAP) : 0;
#pragma unroll
  for (int off = 32; off >= 1; off >>= 1) {
    fp += __shfl_xor(fp, off);
    dr += __shfl_xor(dr, off);
  }
  if (e == 0) { bstat[b] = fp; bstat[8 + b] = (float)dr; }
}

// ---- k3: capacity mask via prefix lookup + one-hot write + finalize --------
__global__ __launch_bounds__(64) void k3_indices(
    const int* __restrict__ prefT, const int* __restrict__ eid_ws,
    const float* __restrict__ bstat, float* __restrict__ out) {
  __shared__ float tile[64][64];
  const int g = blockIdx.x, lane = threadIdx.x; // 64-token chunk
  const int b = g >> 5;
  const int tok = g * 64 + lane;
  const int e = eid_ws[tok];

  unsigned long long mymask = 0ull;             // same-expert mask in chunk
  for (int j = 0; j < 64; ++j) {
    const int ej = __shfl(e, j);
    const unsigned long long bal = __ballot(ej == e);
    if (j == lane) mymask = bal;
  }
  const unsigned long long sub16 = 0xFFFFull << (lane & 48);
  const int lrank = __popcll(mymask & ((1ull << lane) - 1ull) & sub16);
  const int cc = (g & 31) * 4 + (lane >> 4);    // 16-token chunk id in batch
  const int prefix = prefT[((size_t)b * 64 + e) * 128 + cc];
  const float keep = (prefix + lrank < CAP) ? 1.0f : 0.0f;

#pragma unroll
  for (int j = 0; j < 64; ++j) tile[j][lane] = 0.f;
  __syncthreads();
  tile[lane][e] = keep;
  __syncthreads();

  float4*       og = (float4*)(out + (size_t)g * 64 * 64);
  const float4* ts = (const float4*)&tile[0][0];
#pragma unroll
  for (int i = 0; i < 16; ++i) og[i * 64 + lane] = ts[i * 64 + lane];

  if (g == 0 && lane == 0) {                    // finalize aux + dropped
    float s = 0.f, d = 0.f;
#pragma unroll
    for (int i = 0; i < 8; ++i) { s += bstat[i]; d += bstat[8 + i]; }
    out[AUX_OFF] = (float)Ee * s / (float)Bb;
    out[ND_OFF]  = d;
  }
}

extern "C" void kernel_launch(void* const* d_in, const int* in_sizes, int n_in,
                              void* d_out, int out_size, void* d_ws, size_t ws_size,
                              hipStream_t stream) {
  const float* H    = (const float*)d_in[0];
  const float* Wm   = (const float*)d_in[1];
  const float* bias = (const float*)d_in[2];
  float* out = (float*)d_out;
  char*  wsf   = (char*)d_ws + WSF_OFF;
  int*   cntT  = (int*)  ((char*)d_ws + CNTT_OFF);
  float* piT   = (float*)((char*)d_ws + PIT_OFF);
  int*   prefT = (int*)  ((char*)d_ws + PREF_OFF);
  int*   eid   = (int*)  ((char*)d_ws + EID_OFF);
  float* bstat = (float*)((char*)d_ws + BST_OFF);

  hipLaunchKernelGGL(k0_wsplit, dim3(128), dim3(256), 0, stream, Wm, wsf);
  hipLaunchKernelGGL(k1_router, dim3(NB1), dim3(256), 0, stream,
                     H, wsf, bias, out, cntT, piT, eid);
  hipLaunchKernelGGL(k2_scan, dim3(8), dim3(64), 0, stream,
                     cntT, piT, prefT, bstat);
  hipLaunchKernelGGL(k3_indices, dim3(NCHK), dim3(64), 0, stream,
                     prefT, eid, bstat, out);
}

// Round 6
// 144.024 us; speedup vs baseline: 1.2544x; 1.2080x over previous
//
#include <hip/hip_runtime.h>
#include <hip/hip_bf16.h>
#include <stdint.h>

#define Bb 8
#define Ss 2048
#define Dd 4096
#define Ee 64
#define CAP 40
#define M_TOK (Bb*Ss)                   // 16384 tokens
#define TPB 16                          // tokens per k1 block
#define NB1 (M_TOK/TPB)                 // 1024 k1 blocks
#define NCHK (M_TOK/64)                 // 256 k3 blocks
#define TOP1_OFF  (M_TOK*Ee)            // 1048576
#define PROBS_OFF (TOP1_OFF + M_TOK)    // 1064960
#define AUX_OFF   (PROBS_OFF + M_TOK*Ee)// 2113536
#define ND_OFF    (AUX_OFF + 1)

// ws byte offsets
#define WSF_OFF  0u                          // 1 MB fragment-major W hi/lo
#define CNTT_OFF (1u<<20)                    // 256 KB int   cntT[b][e][cc]
#define PIT_OFF  (CNTT_OFF + (256u<<10))     // 256 KB float piT [b][e][cc]
#define PREF_OFF (PIT_OFF  + (256u<<10))     // 256 KB int   prefT[b][e][cc]
#define EID_OFF  (PREF_OFF + (256u<<10))     // 64 KB int    eid[tok]
#define BST_OFF  (EID_OFF  + (64u<<10))      // 16 floats

typedef __attribute__((ext_vector_type(8))) short short8;
typedef __attribute__((ext_vector_type(4))) float f32x4;

// 8 fp32 -> bf16 hi (RNE) + bf16 lo (residual, RNE), packed as short8
__device__ __forceinline__ void cvt8hl(const float4 a, const float4 b,
                                       short8& hi, short8& lo) {
  __hip_bfloat162 h0 = __float22bfloat162_rn(make_float2(a.x, a.y));
  __hip_bfloat162 h1 = __float22bfloat162_rn(make_float2(a.z, a.w));
  __hip_bfloat162 h2 = __float22bfloat162_rn(make_float2(b.x, b.y));
  __hip_bfloat162 h3 = __float22bfloat162_rn(make_float2(b.z, b.w));
  float2 f0 = __bfloat1622float2(h0), f1 = __bfloat1622float2(h1);
  float2 f2 = __bfloat1622float2(h2), f3 = __bfloat1622float2(h3);
  __hip_bfloat162 l0 = __float22bfloat162_rn(make_float2(a.x - f0.x, a.y - f0.y));
  __hip_bfloat162 l1 = __float22bfloat162_rn(make_float2(a.z - f1.x, a.w - f1.y));
  __hip_bfloat162 l2 = __float22bfloat162_rn(make_float2(b.x - f2.x, b.y - f2.y));
  __hip_bfloat162 l3 = __float22bfloat162_rn(make_float2(b.z - f3.x, b.w - f3.y));
  union U { __hip_bfloat162 h[4]; short8 s; };
  U uh; uh.h[0] = h0; uh.h[1] = h1; uh.h[2] = h2; uh.h[3] = h3; hi = uh.s;
  U ul; ul.h[0] = l0; ul.h[1] = l1; ul.h[2] = l2; ul.h[3] = l3; lo = ul.s;
}

// ---- k0: W [k][e] fp32 -> fragment-major hi/lo bf16 ------------------------
// item (g,c,l): lane l of expert-group g, k32-block c. 16B hi @ base, lo @ +1024.
__global__ __launch_bounds__(256) void k0_wsplit(const float* __restrict__ W,
                                                 char* __restrict__ wsf) {
  const int id = blockIdx.x * 256 + threadIdx.x;     // 32768 items
  const int g  = id >> 13;
  const int c  = (id >> 6) & 127;
  const int l  = id & 63;
  const int e  = g * 16 + (l & 15);
  const int kb = c * 32 + (l >> 4) * 8;
  float xs[8];
#pragma unroll
  for (int j = 0; j < 8; ++j) xs[j] = W[(size_t)(kb + j) * Ee + e];
  short8 hi, lo;
  cvt8hl(make_float4(xs[0], xs[1], xs[2], xs[3]),
         make_float4(xs[4], xs[5], xs[6], xs[7]), hi, lo);
  char* base = wsf + (size_t)(g * 128 + c) * 2048 + l * 16;
  *(short8*)base = hi;
  *(short8*)(base + 1024) = lo;
}

// ---- k1: K-split register-direct MFMA + softmax + argmax + chunk stats -----
// Block = 16 tokens, 4 waves. Wave wv owns k32-chunks [wv*32, wv*32+32),
// computes ALL 64 experts (4 groups). H loaded exactly once device-wide.
__global__ __launch_bounds__(256, 4) void k1_router(
    const float* __restrict__ H, const char* __restrict__ wsf,
    const float* __restrict__ bias, float* __restrict__ out,
    int* __restrict__ cntT, float* __restrict__ piT,
    int* __restrict__ eid_ws) {
  __shared__ float pl[4 * 16 * 68];            // per-wave partial logits
  __shared__ int   csh[256];
  __shared__ float psh[256];
  const int tid = threadIdx.x;
  const int wv = tid >> 6, l = tid & 63;
  const int tb = blockIdx.x * TPB;
  const float* hA = H + (size_t)(tb + (l & 15)) * Dd + wv * 1024 + (l >> 4) * 8;
  const char*  bW = wsf + (size_t)(wv * 32) * 2048 + l * 16;

  f32x4 acc0 = {0.f,0.f,0.f,0.f}, acc1 = {0.f,0.f,0.f,0.f};
  f32x4 acc2 = {0.f,0.f,0.f,0.f}, acc3 = {0.f,0.f,0.f,0.f};
  float4 aX0, aX1, aY0, aY1;                   // A depth-2 prefetch (2 sets)
  short8 wA0, wA1, wA2, wA3;                   // W groups 0,1 (hi/lo each)
  short8 wB0, wB1, wB2, wB3;                   // W groups 2,3 (hi/lo each)

#define LDA(r0, r1, c) { const float* p = hA + (c) * 32;                      \
    r0 = *(const float4*)p; r1 = *(const float4*)(p + 4); }
#define LDW2(r0, r1, r2, r3, c, gbase) {                                      \
    const char* p = bW + (size_t)(c) * 2048 + (size_t)(gbase) * 262144;       \
    r0 = *(const short8*)p;            r1 = *(const short8*)(p + 1024);       \
    r2 = *(const short8*)(p + 262144); r3 = *(const short8*)(p + 262144 + 1024); }
#define MFMA4(ac, ah, al, wh, wl) {                                           \
    ac = __builtin_amdgcn_mfma_f32_16x16x32_bf16(ah, wh, ac, 0, 0, 0);        \
    ac = __builtin_amdgcn_mfma_f32_16x16x32_bf16(ah, wl, ac, 0, 0, 0);        \
    ac = __builtin_amdgcn_mfma_f32_16x16x32_bf16(al, wh, ac, 0, 0, 0);        \
    ac = __builtin_amdgcn_mfma_f32_16x16x32_bf16(al, wl, ac, 0, 0, 0); }

  // body for chunk c: consumes A set (aU), reloads it for chunk c+2.
  // wA holds groups 0,1 of c on entry; reloaded for c+1 mid-body.
#define BODY(aU0, aU1, c) {                                                   \
    LDW2(wB0, wB1, wB2, wB3, (c), 2);          /* groups 2,3 of c */          \
    short8 ah, al;                                                            \
    cvt8hl(aU0, aU1, ah, al);                                                 \
    { const int cn = ((c) + 2 < 32) ? (c) + 2 : 31;                           \
      LDA(aU0, aU1, cn); }                                                    \
    MFMA4(acc0, ah, al, wA0, wA1);                                            \
    MFMA4(acc1, ah, al, wA2, wA3);                                            \
    { const int cw = ((c) + 1 < 32) ? (c) + 1 : 31;                           \
      LDW2(wA0, wA1, wA2, wA3, cw, 0); }       /* groups 0,1 of next */       \
    MFMA4(acc2, ah, al, wB0, wB1);                                            \
    MFMA4(acc3, ah, al, wB2, wB3); }

  LDA(aX0, aX1, 0); LDA(aY0, aY1, 1);
  LDW2(wA0, wA1, wA2, wA3, 0, 0);
  for (int cc = 0; cc < 16; ++cc) {
    BODY(aX0, aX1, 2 * cc);
    BODY(aY0, aY1, 2 * cc + 1);
  }

  // ---- cross-wave k-reduction via LDS, then softmax/argmax ----------------
  float* myp = pl + wv * 1088;                 // [16][68] per wave
  const int r0 = (l >> 4) * 4;
  const int c0 = l & 15;
#pragma unroll
  for (int r = 0; r < 4; ++r) {
    myp[(r0 + r) * 68 + c0     ] = acc0[r];
    myp[(r0 + r) * 68 + 16 + c0] = acc1[r];
    myp[(r0 + r) * 68 + 32 + c0] = acc2[r];
    myp[(r0 + r) * 68 + 48 + c0] = acc3[r];
  }
  __syncthreads();

  int cnt = 0; float pis = 0.f;
  const float bl_ = bias[l];
#pragma unroll
  for (int i = 0; i < 4; ++i) {                // wave owns 4 rows, lane=expert
    const int t = wv * 4 + i, tok = tb + t;
    const float v = pl[t * 68 + l] + pl[1088 + t * 68 + l] +
                    pl[2176 + t * 68 + l] + pl[3264 + t * 68 + l] + bl_;
    float m = v; int mi = l;
#pragma unroll
    for (int off = 32; off >= 1; off >>= 1) {  // max + first-index argmax
      const float ov = __shfl_xor(m, off);
      const int   oi = __shfl_xor(mi, off);
      if (ov > m || (ov == m && oi < mi)) { m = ov; mi = oi; }
    }
    const float ex = __expf(v - m);
    float ssum = ex;
#pragma unroll
    for (int off = 32; off >= 1; off >>= 1) ssum += __shfl_xor(ssum, off);
    const float inv = 1.0f / ssum;
    const float p = ex * inv;
    out[(size_t)PROBS_OFF + (size_t)tok * Ee + l] = p;
    if (l == 0) {
      out[TOP1_OFF + tok] = inv;               // max prob = 1/sum
      eid_ws[tok] = mi;
    }
    cnt += (mi == l) ? 1 : 0;
    pis += p;
  }
  csh[wv * 64 + l] = cnt;
  psh[wv * 64 + l] = pis;
  __syncthreads();
  if (tid < 64) {
    const int   ct = csh[tid] + csh[64 + tid] + csh[128 + tid] + csh[192 + tid];
    const float pp = psh[tid] + psh[64 + tid] + psh[128 + tid] + psh[192 + tid];
    const int b = blockIdx.x >> 7, cc = blockIdx.x & 127;
    cntT[((size_t)b * 64 + tid) * 128 + cc] = ct;
    piT [((size_t)b * 64 + tid) * 128 + cc] = pp;
  }
}

// ---- k2: per-(b,e) exclusive prefix over 128 chunks + per-b aux stats ------
__global__ __launch_bounds__(64) void k2_scan(const int* __restrict__ cntT,
                                              const float* __restrict__ piT,
                                              int* __restrict__ prefT,
                                              float* __restrict__ bstat) {
  const int b = blockIdx.x, e = threadIdx.x;   // 8 blocks x 64 lanes
  const int4* src = (const int4*)(cntT + ((size_t)b * 64 + e) * 128);
  int4*       dst = (int4*)(prefT + ((size_t)b * 64 + e) * 128);
  int run = 0;
#pragma unroll 8
  for (int t = 0; t < 32; ++t) {
    const int4 v = src[t];
    int4 o;
    o.x = run; o.y = o.x + v.x; o.z = o.y + v.y; o.w = o.z + v.z;
    run = o.w + v.w;
    dst[t] = o;
  }
  const int tot = run;
  float ps = 0.f;
  const float4* pp = (const float4*)(piT + ((size_t)b * 64 + e) * 128);
#pragma unroll 8
  for (int t = 0; t < 32; ++t) { const float4 v = pp[t]; ps += v.x + v.y + v.z + v.w; }
  const float fi = (float)((tot < CAP) ? tot : CAP) * (1.0f / (float)Ss);
  const float pi = ps * (1.0f / (float)Ss);
  float fp = fi * pi;
  int   dr = (tot > CAP) ? (tot - CAP) : 0;
#pragma unroll
  for (int off = 32; off >= 1; off >>= 1) {
    fp += __shfl_xor(fp, off);
    dr += __shfl_xor(dr, off);
  }
  if (e == 0) { bstat[b] = fp; bstat[8 + b] = (float)dr; }
}

// ---- k3: capacity mask via prefix lookup + one-hot write + finalize --------
__global__ __launch_bounds__(64) void k3_indices(
    const int* __restrict__ prefT, const int* __restrict__ eid_ws,
    const float* __restrict__ bstat, float* __restrict__ out) {
  __shared__ float tile[64][64];
  const int g = blockIdx.x, lane = threadIdx.x; // 64-token chunk
  const int b = g >> 5;
  const int tok = g * 64 + lane;
  const int e = eid_ws[tok];

  unsigned long long mymask = 0ull;             // same-expert mask in chunk
  for (int j = 0; j < 64; ++j) {
    const int ej = __shfl(e, j);
    const unsigned long long bal = __ballot(ej == e);
    if (j == lane) mymask = bal;
  }
  const unsigned long long sub16 = 0xFFFFull << (lane & 48);
  const int lrank = __popcll(mymask & ((1ull << lane) - 1ull) & sub16);
  const int cc = (g & 31) * 4 + (lane >> 4);    // 16-token chunk id in batch
  const int prefix = prefT[((size_t)b * 64 + e) * 128 + cc];
  const float keep = (prefix + lrank < CAP) ? 1.0f : 0.0f;

#pragma unroll
  for (int j = 0; j < 64; ++j) tile[j][lane] = 0.f;
  __syncthreads();
  tile[lane][e] = keep;
  __syncthreads();

  float4*       og = (float4*)(out + (size_t)g * 64 * 64);
  const float4* ts = (const float4*)&tile[0][0];
#pragma unroll
  for (int i = 0; i < 16; ++i) og[i * 64 + lane] = ts[i * 64 + lane];

  if (g == 0 && lane == 0) {                    // finalize aux + dropped
    float s = 0.f, d = 0.f;
#pragma unroll
    for (int i = 0; i < 8; ++i) { s += bstat[i]; d += bstat[8 + i]; }
    out[AUX_OFF] = (float)Ee * s / (float)Bb;
    out[ND_OFF]  = d;
  }
}

extern "C" void kernel_launch(void* const* d_in, const int* in_sizes, int n_in,
                              void* d_out, int out_size, void* d_ws, size_t ws_size,
                              hipStream_t stream) {
  const float* H    = (const float*)d_in[0];
  const float* Wm   = (const float*)d_in[1];
  const float* bias = (const float*)d_in[2];
  float* out = (float*)d_out;
  char*  wsf   = (char*)d_ws + WSF_OFF;
  int*   cntT  = (int*)  ((char*)d_ws + CNTT_OFF);
  float* piT   = (float*)((char*)d_ws + PIT_OFF);
  int*   prefT = (int*)  ((char*)d_ws + PREF_OFF);
  int*   eid   = (int*)  ((char*)d_ws + EID_OFF);
  float* bstat = (float*)((char*)d_ws + BST_OFF);

  hipLaunchKernelGGL(k0_wsplit, dim3(128), dim3(256), 0, stream, Wm, wsf);
  hipLaunchKernelGGL(k1_router, dim3(NB1), dim3(256), 0, stream,
                     H, wsf, bias, out, cntT, piT, eid);
  hipLaunchKernelGGL(k2_scan, dim3(8), dim3(64), 0, stream,
                     cntT, piT, prefT, bstat);
  hipLaunchKernelGGL(k3_indices, dim3(NCHK), dim3(64), 0, stream,
                     prefT, eid, bstat, out);
}

// Round 8
// 89.988 us; speedup vs baseline: 2.0076x; 1.6005x over previous
//
#include <hip/hip_runtime.h>
#include <hip/hip_bf16.h>
#include <stdint.h>

#define Bb 8
#define Ss 2048
#define Dd 4096
#define Ee 64
#define CAP 40
#define M_TOK (Bb*Ss)                    // 16384 tokens
#define TOP1_OFF  (M_TOK*Ee)             // 1048576
#define PROBS_OFF (TOP1_OFF + M_TOK)     // 1064960
#define AUX_OFF   (PROBS_OFF + M_TOK*Ee) // 2113536
#define ND_OFF    (AUX_OFF + 1)

// ws byte offsets
#define W2_OFF   0u                      // 1 MB chunk-major W hi/lo
#define PART_OFF (1u<<20)                // 16 MB fp32 partials [tg][ks][64][64]
#define CNTT_OFF (17u<<20)               // 64 KB int   cntT[b][e][32]
#define PIT_OFF  ((17u<<20) + (64u<<10))
#define PREF_OFF ((17u<<20) + (128u<<10))
#define EID_OFF  ((17u<<20) + (192u<<10))
#define BST_OFF  ((17u<<20) + (256u<<10))

typedef __attribute__((ext_vector_type(8))) short short8;
typedef __attribute__((ext_vector_type(4))) float f32x4;

// pin vmem issue order across this point (IR + MIR schedulers)
#define FENCE() do {                                                          \
    asm volatile("" ::: "memory");                                            \
    __builtin_amdgcn_sched_barrier(0);                                        \
  } while (0)

__device__ __forceinline__ void cvt8hl(const float4 a, const float4 b,
                                       short8& hi, short8& lo) {
  __hip_bfloat162 h0 = __float22bfloat162_rn(make_float2(a.x, a.y));
  __hip_bfloat162 h1 = __float22bfloat162_rn(make_float2(a.z, a.w));
  __hip_bfloat162 h2 = __float22bfloat162_rn(make_float2(b.x, b.y));
  __hip_bfloat162 h3 = __float22bfloat162_rn(make_float2(b.z, b.w));
  float2 f0 = __bfloat1622float2(h0), f1 = __bfloat1622float2(h1);
  float2 f2 = __bfloat1622float2(h2), f3 = __bfloat1622float2(h3);
  __hip_bfloat162 l0 = __float22bfloat162_rn(make_float2(a.x - f0.x, a.y - f0.y));
  __hip_bfloat162 l1 = __float22bfloat162_rn(make_float2(a.z - f1.x, a.w - f1.y));
  __hip_bfloat162 l2 = __float22bfloat162_rn(make_float2(b.x - f2.x, b.y - f2.y));
  __hip_bfloat162 l3 = __float22bfloat162_rn(make_float2(b.z - f3.x, b.w - f3.y));
  union U { __hip_bfloat162 h[4]; short8 s; };
  U uh; uh.h[0] = h0; uh.h[1] = h1; uh.h[2] = h2; uh.h[3] = h3; hi = uh.s;
  U ul; ul.h[0] = l0; ul.h[1] = l1; ul.h[2] = l2; ul.h[3] = l3; lo = ul.s;
}

// ---- k0: W [k][e] fp32 -> chunk-major hi/lo bf16 fragments -----------------
// chunk c (k64) = 16KB: [sub(2)][g(4)][hl(2)][lane(64)x16B]
__global__ __launch_bounds__(256) void k0_wsplit(const float* __restrict__ W,
                                                 char* __restrict__ w2) {
  const int id  = blockIdx.x * 256 + threadIdx.x;   // 32768 items
  const int l   = id & 63;
  const int g   = (id >> 6) & 3;
  const int sub = (id >> 8) & 1;
  const int c   = id >> 9;
  const int e   = g * 16 + (l & 15);
  const int kb  = c * 64 + sub * 32 + (l >> 4) * 8;
  float xs[8];
#pragma unroll
  for (int j = 0; j < 8; ++j) xs[j] = W[(size_t)(kb + j) * Ee + e];
  short8 hi, lo;
  cvt8hl(make_float4(xs[0], xs[1], xs[2], xs[3]),
         make_float4(xs[4], xs[5], xs[6], xs[7]), hi, lo);
  char* base = w2 + (size_t)c * 16384 + sub * 8192 + g * 2048 + l * 16;
  *(short8*)base = hi;
  *(short8*)(base + 1024) = lo;
}

// ---- k1: 64-token x K-quarter MFMA partial GEMM ----------------------------
// grid 1024: tg = bid>>2 (64 tokens), ks = bid&3 (k-quarter). 4 waves:
// wave = 16 tokens x 64 experts. W staged via global_load_lds (dbuf 2x16KB).
// Issue order pinned: STAGE -> (cvt, LDA) -> COMPM -> vmcnt(4) -> barrier.
__global__ __launch_bounds__(256, 4) void k1_gemm(
    const float* __restrict__ H, const char* __restrict__ w2,
    float* __restrict__ part) {
  __shared__ char wb[2][16384];
  const int tid = threadIdx.x;
  const int wv = tid >> 6, l = tid & 63;
  const int tg = blockIdx.x >> 2, ks = blockIdx.x & 3;
  const float* hA = H + (size_t)(tg * 64 + wv * 16 + (l & 15)) * Dd
                      + ks * 1024 + (l >> 4) * 8;
  const char* wsrc = w2 + (size_t)ks * 262144 + wv * 4096 + l * 16;

  f32x4 acc[4];
#pragma unroll
  for (int g = 0; g < 4; ++g) acc[g] = (f32x4){0.f, 0.f, 0.f, 0.f};

  float4 aX0, aX1, aX2, aX3, aY0, aY1, aY2, aY3;   // depth-2 A prefetch
  short8 ah0, al0, ah1, al1;

#define GLL16(gs, ls)                                                         \
  __builtin_amdgcn_global_load_lds(                                           \
      (const __attribute__((address_space(1))) unsigned int*)(gs),            \
      (__attribute__((address_space(3))) unsigned int*)(ls), 16, 0, 0)

#define STAGE(t, bi) {                                                        \
    const char* s_ = wsrc + (size_t)(t) * 16384;                              \
    char* d_ = &wb[bi][wv * 4096];                                            \
    GLL16(s_, d_);                 GLL16(s_ + 1024, d_ + 1024);               \
    GLL16(s_ + 2048, d_ + 2048);   GLL16(s_ + 3072, d_ + 3072); }

#define LDA(r0, r1, r2, r3, t) { const float* p_ = hA + (t) * 64;             \
    r0 = *(const float4*)(p_);      r1 = *(const float4*)(p_ + 4);            \
    r2 = *(const float4*)(p_ + 32); r3 = *(const float4*)(p_ + 36); }

#define MFMA4(ac, ah, al, wh, wl) {                                           \
    ac = __builtin_amdgcn_mfma_f32_16x16x32_bf16(ah, wh, ac, 0, 0, 0);        \
    ac = __builtin_amdgcn_mfma_f32_16x16x32_bf16(ah, wl, ac, 0, 0, 0);        \
    ac = __builtin_amdgcn_mfma_f32_16x16x32_bf16(al, wh, ac, 0, 0, 0);        \
    ac = __builtin_amdgcn_mfma_f32_16x16x32_bf16(al, wl, ac, 0, 0, 0); }

#define COMPM(bi) { const char* wp_ = &wb[bi][0] + l * 16;                    \
    _Pragma("unroll")                                                         \
    for (int g = 0; g < 4; ++g) {                                             \
      const short8 wh0 = *(const short8*)(wp_ + g * 2048);                    \
      const short8 wl0 = *(const short8*)(wp_ + g * 2048 + 1024);             \
      MFMA4(acc[g], ah0, al0, wh0, wl0);                                      \
      const short8 wh1 = *(const short8*)(wp_ + 8192 + g * 2048);             \
      const short8 wl1 = *(const short8*)(wp_ + 8192 + g * 2048 + 1024);      \
      MFMA4(acc[g], ah1, al1, wh1, wl1);                                      \
    } }

  // prologue: STAGE(0) issued FIRST (oldest) -> vmcnt(8) retires it
  STAGE(0, 0);
  FENCE();
  LDA(aX0, aX1, aX2, aX3, 0);
  LDA(aY0, aY1, aY2, aY3, 1);
  FENCE();
  asm volatile("s_waitcnt vmcnt(8)" ::: "memory");   // W chunk 0 landed
  __builtin_amdgcn_s_barrier();

#pragma unroll
  for (int t = 0; t < 16; ++t) {
    const int bi = t & 1;
    if (t < 15) STAGE(t + 1, bi ^ 1);                // issued first (older)
    FENCE();
    if ((t & 1) == 0) {
      cvt8hl(aX0, aX1, ah0, al0); cvt8hl(aX2, aX3, ah1, al1);
      if (t < 14) LDA(aX0, aX1, aX2, aX3, t + 2);    // issued last (newest)
    } else {
      cvt8hl(aY0, aY1, ah0, al0); cvt8hl(aY2, aY3, ah1, al1);
      if (t < 14) LDA(aY0, aY1, aY2, aY3, t + 2);
    }
    FENCE();
    COMPM(bi);
    // outstanding (issue order): LDA(t+1) | STAGE(t+1) | LDA(t+2)
    // vmcnt(4) leaves only LDA(t+2) -> STAGE(t+1) complete before next read
    if (t < 14)       { asm volatile("s_waitcnt vmcnt(4)" ::: "memory"); }
    else if (t == 14) { asm volatile("s_waitcnt vmcnt(0)" ::: "memory"); }
    if (t < 15) __builtin_amdgcn_s_barrier();
  }

  // partial logits -> ws (fp32), [tg][ks][tok64][e]
  float* pp = part + (size_t)(tg * 4 + ks) * 4096;
#pragma unroll
  for (int g = 0; g < 4; ++g)
#pragma unroll
    for (int r = 0; r < 4; ++r)
      pp[(wv * 16 + (l >> 4) * 4 + r) * 64 + g * 16 + (l & 15)] = acc[g][r];
}

// ---- k1b: sum 4 k-partials + bias, softmax, argmax, chunk stats ------------
__global__ __launch_bounds__(512) void k1b_softmax(
    const float* __restrict__ part, const float* __restrict__ bias,
    float* __restrict__ out, int* __restrict__ cntT, float* __restrict__ piT,
    int* __restrict__ eid_ws) {
  __shared__ int   csh[512];
  __shared__ float psh[512];
  const int tid = threadIdx.x, wv = tid >> 6, l = tid & 63;
  const int tg = blockIdx.x;
  const float* p0 = part + (size_t)tg * 16384;

  int cnt = 0; float pis = 0.f;
  const float bl_ = bias[l];
#pragma unroll
  for (int i = 0; i < 8; ++i) {                 // wave owns 8 tokens
    const int t = wv * 8 + i, tok = tg * 64 + t;
    const float v = p0[t * 64 + l] + p0[4096 + t * 64 + l] +
                    p0[8192 + t * 64 + l] + p0[12288 + t * 64 + l] + bl_;
    float m = v; int mi = l;
#pragma unroll
    for (int off = 32; off >= 1; off >>= 1) {   // max + first-index argmax
      const float ov = __shfl_xor(m, off);
      const int   oi = __shfl_xor(mi, off);
      if (ov > m || (ov == m && oi < mi)) { m = ov; mi = oi; }
    }
    const float ex = __expf(v - m);
    float ssum = ex;
#pragma unroll
    for (int off = 32; off >= 1; off >>= 1) ssum += __shfl_xor(ssum, off);
    const float inv = 1.0f / ssum;
    const float p = ex * inv;
    out[(size_t)PROBS_OFF + (size_t)tok * Ee + l] = p;
    if (l == 0) {
      out[TOP1_OFF + tok] = inv;                // max prob = 1/sum
      eid_ws[tok] = mi;
    }
    cnt += (mi == l) ? 1 : 0;
    pis += p;
  }
  csh[wv * 64 + l] = cnt;
  psh[wv * 64 + l] = pis;
  __syncthreads();
  if (tid < 64) {
    int ct = 0; float pp = 0.f;
#pragma unroll
    for (int w = 0; w < 8; ++w) { ct += csh[w * 64 + tid]; pp += psh[w * 64 + tid]; }
    cntT[((size_t)(tg >> 5) * 64 + tid) * 32 + (tg & 31)] = ct;
    piT [((size_t)(tg >> 5) * 64 + tid) * 32 + (tg & 31)] = pp;
  }
}

// ---- k2: per-(b,e) exclusive prefix over 32 chunks + per-b aux stats -------
__global__ __launch_bounds__(64) void k2_scan(const int* __restrict__ cntT,
                                              const float* __restrict__ piT,
                                              int* __restrict__ prefT,
                                              float* __restrict__ bstat) {
  const int b = blockIdx.x, e = threadIdx.x;    // 8 blocks x 64 lanes
  const int4* src = (const int4*)(cntT + ((size_t)b * 64 + e) * 32);
  int4*       dst = (int4*)(prefT + ((size_t)b * 64 + e) * 32);
  int run = 0;
#pragma unroll
  for (int t = 0; t < 8; ++t) {
    const int4 v = src[t];
    int4 o;
    o.x = run; o.y = o.x + v.x; o.z = o.y + v.y; o.w = o.z + v.z;
    run = o.w + v.w;
    dst[t] = o;
  }
  const int tot = run;
  float ps = 0.f;
  const float4* pp = (const float4*)(piT + ((size_t)b * 64 + e) * 32);
#pragma unroll
  for (int t = 0; t < 8; ++t) { const float4 v = pp[t]; ps += v.x + v.y + v.z + v.w; }
  const float fi = (float)((tot < CAP) ? tot : CAP) * (1.0f / (float)Ss);
  const float pi = ps * (1.0f / (float)Ss);
  float fp = fi * pi;
  int   dr = (tot > CAP) ? (tot - CAP) : 0;
#pragma unroll
  for (int off = 32; off >= 1; off >>= 1) {
    fp += __shfl_xor(fp, off);
    dr += __shfl_xor(dr, off);
  }
  if (e == 0) { bstat[b] = fp; bstat[8 + b] = (float)dr; }
}

// ---- k3: capacity mask via prefix lookup + one-hot write + finalize --------
__global__ __launch_bounds__(64) void k3_indices(
    const int* __restrict__ prefT, const int* __restrict__ eid_ws,
    const float* __restrict__ bstat, float* __restrict__ out) {
  __shared__ float tile[64][64];
  const int g = blockIdx.x, lane = threadIdx.x; // 64-token chunk
  const int b = g >> 5;
  const int tok = g * 64 + lane;
  const int e = eid_ws[tok];

  unsigned long long mymask = 0ull;             // same-expert mask in chunk
  for (int j = 0; j < 64; ++j) {
    const int ej = __shfl(e, j);
    const unsigned long long bal = __ballot(ej == e);
    if (j == lane) mymask = bal;
  }
  const int lrank = __popcll(mymask & ((1ull << lane) - 1ull));
  const int prefix = prefT[((size_t)b * 64 + e) * 32 + (g & 31)];
  const float keep = (prefix + lrank < CAP) ? 1.0f : 0.0f;

#pragma unroll
  for (int j = 0; j < 64; ++j) tile[j][lane] = 0.f;
  __syncthreads();
  tile[lane][e] = keep;
  __syncthreads();

  float4*       og = (float4*)(out + (size_t)g * 64 * 64);
  const float4* ts = (const float4*)&tile[0][0];
#pragma unroll
  for (int i = 0; i < 16; ++i) og[i * 64 + lane] = ts[i * 64 + lane];

  if (g == 0 && lane == 0) {                    // finalize aux + dropped
    float s = 0.f, d = 0.f;
#pragma unroll
    for (int i = 0; i < 8; ++i) { s += bstat[i]; d += bstat[8 + i]; }
    out[AUX_OFF] = (float)Ee * s / (float)Bb;
    out[ND_OFF]  = d;
  }
}

extern "C" void kernel_launch(void* const* d_in, const int* in_sizes, int n_in,
                              void* d_out, int out_size, void* d_ws, size_t ws_size,
                              hipStream_t stream) {
  const float* H    = (const float*)d_in[0];
  const float* Wm   = (const float*)d_in[1];
  const float* bias = (const float*)d_in[2];
  float* out = (float*)d_out;
  char*  w2    = (char*) d_ws + W2_OFF;
  float* part  = (float*)((char*)d_ws + PART_OFF);
  int*   cntT  = (int*)  ((char*)d_ws + CNTT_OFF);
  float* piT   = (float*)((char*)d_ws + PIT_OFF);
  int*   prefT = (int*)  ((char*)d_ws + PREF_OFF);
  int*   eid   = (int*)  ((char*)d_ws + EID_OFF);
  float* bstat = (float*)((char*)d_ws + BST_OFF);

  hipLaunchKernelGGL(k0_wsplit,   dim3(128),  dim3(256), 0, stream, Wm, w2);
  hipLaunchKernelGGL(k1_gemm,     dim3(1024), dim3(256), 0, stream, H, w2, part);
  hipLaunchKernelGGL(k1b_softmax, dim3(256),  dim3(512), 0, stream,
                     part, bias, out, cntT, piT, eid);
  hipLaunchKernelGGL(k2_scan,     dim3(8),    dim3(64),  0, stream,
                     cntT, piT, prefT, bstat);
  hipLaunchKernelGGL(k3_indices,  dim3(256),  dim3(64),  0, stream,
                     prefT, eid, bstat, out);
}